// Round 3
// baseline (25.681 us; speedup 1.0000x reference)
//
#include <hip/hip_runtime.h>

typedef short  bf16x8 __attribute__((ext_vector_type(8)));
typedef float  f32x4  __attribute__((ext_vector_type(4)));

#define HP 4

// ---------------------------------------------------------------------------
// Fused kernel: one block per (n, i) center-row. 224 blocks, 256 threads.
// Phase 1: load A-row i and B-rows i-4..i+4 from fp32 (n,c,h,w), channel-
//          normalize, convert to bf16 into LDS tiles [w][72] (padded stride).
// Phase 2: 9 di-steps x 8 MFMA (16x16x32 bf16) from LDS, band-masked
//          sum-of-exp + sum-of-x (no max needed: |dot| <= ~1.03).
// ---------------------------------------------------------------------------
__global__ __launch_bounds__(256) void fused_kernel(const float* __restrict__ A,
                                                    const float* __restrict__ B,
                                                    float* __restrict__ partials) {
    __shared__ ushort bt[9][64][72];   // 82,944 B  (B-rows, bf16, padded)
    __shared__ ushort at[64][72];      //  9,216 B  (A-row)
    __shared__ float  scratch[64 * 65];// 16,640 B  ([w][c] fp32 staging)
    __shared__ float  invs[64];
    __shared__ float  red[16];

    const int b   = blockIdx.x;          // 0..223
    const int n   = b / 56;
    const int i   = b - n * 56 + HP;     // 4..59
    const int t   = threadIdx.x;

    // ---- Phase 1: normalize 10 rows (r=0..8 -> B row i-4+r, r=9 -> A row i)
    for (int r = 0; r < 10; ++r) {
        const float* src = (r == 9) ? A : B;
        const int hrow   = (r == 9) ? i : (i - HP + r);
        const size_t ibase = (size_t)n * 262144 + (size_t)hrow * 64;

        #pragma unroll
        for (int k = 0; k < 16; ++k) {
            int idx = k * 256 + t;
            int c = idx >> 6, w = idx & 63;
            scratch[w * 65 + c] = src[ibase + (size_t)c * 4096 + w];
        }
        __syncthreads();
        {
            int w = t >> 2, q = t & 3;
            float ss = 0.f;
            #pragma unroll
            for (int k = 0; k < 16; ++k) { float v = scratch[w * 65 + q + 4 * k]; ss += v * v; }
            ss += __shfl_xor(ss, 1);
            ss += __shfl_xor(ss, 2);
            if (q == 0) invs[w] = 1.0f / (sqrtf(ss) + 1e-8f);
        }
        __syncthreads();
        {
            uint* dst = (r == 9) ? (uint*)&at[0][0] : (uint*)&bt[r][0][0];
            #pragma unroll
            for (int k = 0; k < 8; ++k) {
                int idx2 = k * 256 + t;          // uint index: w = idx2>>5, cpair = idx2&31
                int w = idx2 >> 5;
                int c = (idx2 & 31) * 2;
                float inv = invs[w];
                float v0 = scratch[w * 65 + c]     * inv;
                float v1 = scratch[w * 65 + c + 1] * inv;
                uint u0 = __float_as_uint(v0); u0 = (u0 + 0x7FFFu + ((u0 >> 16) & 1)) >> 16;
                uint u1 = __float_as_uint(v1); u1 = (u1 + 0x7FFFu + ((u1 >> 16) & 1)) >> 16;
                dst[w * 36 + (idx2 & 31)] = u0 | (u1 << 16);
            }
        }
        __syncthreads();
    }

    // ---- Phase 2: MFMA band correlation + sum-of-exp
    const int wib = t >> 6, l = t & 63;
    const int lo  = l & 15, hi = l >> 4;
    const int j0  = HP + wib * 16;

    const bf16x8 a0 = *(const bf16x8*)&at[j0 + lo][hi * 8];
    const bf16x8 a1 = *(const bf16x8*)&at[j0 + lo][hi * 8 + 32];

    int jrow[4];
    #pragma unroll
    for (int r = 0; r < 4; ++r) jrow[r] = j0 + hi * 4 + r;
    float vmask[4][4];
    #pragma unroll
    for (int nt = 0; nt < 4; ++nt) {
        int col = nt * 16 + lo;
        #pragma unroll
        for (int r = 0; r < 4; ++r) {
            int d = col - jrow[r];
            vmask[nt][r] = (jrow[r] < 60 && d >= -HP && d <= HP) ? 1.0f : 0.0f;
        }
    }

    float s_acc[4]  = {0.f, 0.f, 0.f, 0.f};
    float sx_acc[4] = {0.f, 0.f, 0.f, 0.f};

    #pragma unroll
    for (int di = 0; di < 9; ++di) {
        const ushort* bp = &bt[di][0][0];
        #pragma unroll
        for (int nt = 0; nt < 4; ++nt) {
            const ushort* q = bp + (nt * 16 + lo) * 72 + hi * 8;
            bf16x8 b0 = *(const bf16x8*)q;
            bf16x8 b1 = *(const bf16x8*)(q + 32);
            f32x4 acc = __builtin_amdgcn_mfma_f32_16x16x32_bf16(a0, b0,
                            (f32x4){0.f, 0.f, 0.f, 0.f}, 0, 0, 0);
            acc = __builtin_amdgcn_mfma_f32_16x16x32_bf16(a1, b1, acc, 0, 0, 0);
            #pragma unroll
            for (int r = 0; r < 4; ++r) {
                float p = acc[r];
                float e = __expf(p);
                s_acc[r]  = fmaf(vmask[nt][r], e, s_acc[r]);
                sx_acc[r] = fmaf(vmask[nt][r], p, sx_acc[r]);
            }
        }
    }

    // Reduce across the 16 lanes (cols) sharing each output row
    #pragma unroll
    for (int r = 0; r < 4; ++r) {
        #pragma unroll
        for (int off = 1; off < 16; off <<= 1) {
            s_acc[r]  += __shfl_xor(s_acc[r],  off);
            sx_acc[r] += __shfl_xor(sx_acc[r], off);
        }
    }
    if (lo == 0) {
        float csum = 0.f;
        #pragma unroll
        for (int r = 0; r < 4; ++r)
            if (jrow[r] < 60) csum += 81.0f * __logf(s_acc[r]) - sx_acc[r];
        red[wib * 4 + hi] = csum;
    }
    __syncthreads();
    if (t == 0) {
        float t2 = 0.f;
        #pragma unroll
        for (int k = 0; k < 16; ++k) t2 += red[k];
        partials[b] = t2;
    }
}

// ---------------------------------------------------------------------------
// Final reduce: one wave sums 224 partials -> d_out[0]
// ---------------------------------------------------------------------------
__global__ __launch_bounds__(64) void reduce_kernel(const float* __restrict__ partials,
                                                    float* __restrict__ out) {
    const int t = threadIdx.x;
    float s = 0.f;
    #pragma unroll
    for (int k = 0; k < 4; ++k) {
        int idx = k * 64 + t;
        if (idx < 224) s += partials[idx];
    }
    #pragma unroll
    for (int off = 32; off; off >>= 1) s += __shfl_xor(s, off);
    if (t == 0) out[0] = s;
}

extern "C" void kernel_launch(void* const* d_in, const int* in_sizes, int n_in,
                              void* d_out, int out_size, void* d_ws, size_t ws_size,
                              hipStream_t stream) {
    // inputs: 0=featsA(unused) 1=warpedA 2=tensorB 3=warp_grid(unused) 4=patch_size(=9)
    const float* warpedA = (const float*)d_in[1];
    const float* tensorB = (const float*)d_in[2];
    float* partials = (float*)d_ws;          // 224 floats
    float* out = (float*)d_out;

    fused_kernel<<<224, 256, 0, stream>>>(warpedA, tensorB, partials);
    reduce_kernel<<<1, 64, 0, stream>>>(partials, out);
}

// Round 4
// 15.757 us; speedup vs baseline: 1.6298x; 1.6298x over previous
//
#include <hip/hip_runtime.h>

typedef short  bf16x8 __attribute__((ext_vector_type(8)));
typedef float  f32x4  __attribute__((ext_vector_type(4)));

#define HP 4

// ---------------------------------------------------------------------------
// Fused kernel v2: one block per (n, i) center-row. 224 blocks, 256 threads.
//
// Phase 1 (ONE barrier total, waves independent): the 10 needed rows
// (9 B-rows i-4..i+4, 1 A-row i) are split across the 4 waves (wave w gets
// rows w, w+4, w+8). Per row, lane = w-coordinate: loop c, load fp32
// (coalesced), accumulate ss per-lane (no cross-lane reduce!), RTN-convert
// RAW value to bf16, pack 8-wide, one ds_write_b128 per 8 channels.
// Norms are applied AFTER the MFMA: dot(a^,b^) = raw_dot * inva[j] * invb[j'].
//
// Phase 2: band correlation. Per wave only the 2 column tiles its 16-row
// band touches (wave 3: 1 tile) -> 36 (18) MFMAs; epilogue scales by
// inva*invb, band-masks, accumulates sum-exp + sum-x.
// ---------------------------------------------------------------------------
__global__ __launch_bounds__(256) void fused_kernel(const float* __restrict__ A,
                                                    const float* __restrict__ B,
                                                    float* __restrict__ partials) {
    __shared__ ushort bt[9][64][72];   // 82,944 B raw-bf16 B rows (stride 72: conflict-free b128)
    __shared__ ushort at[64][72];      //  9,216 B raw-bf16 A row
    __shared__ float  binv[9][64];     //  2,304 B inverse norms of B rows
    __shared__ float  ainv_s[64];      //    256 B inverse norms of A row
    __shared__ float  red[16];

    // Bijective XCD swizzle (224 = 8 XCD * 28): i-neighbors share an L2
    const int b0 = blockIdx.x;
    const int b  = (b0 & 7) * 28 + (b0 >> 3);
    const int n  = b / 56;
    const int i  = b - n * 56 + HP;          // 4..59
    const int t  = threadIdx.x, wib = t >> 6, l = t & 63;

    // ---- Phase 1: waves independently stage their rows
    for (int rr = 0; rr < 3; ++rr) {
        const int r = wib + rr * 4;          // wave0:0,4,8  w1:1,5,9  w2:2,6  w3:3,7
        if (r > 9) break;                    // wave-uniform
        const int hrow = (r == 9) ? i : (i - HP + r);
        const float* src = ((r == 9) ? A : B) + (size_t)n * 262144 + (size_t)hrow * 64 + l;
        ushort* dst = ((r == 9) ? &at[0][0] : &bt[r][0][0]) + l * 72;
        float ss = 0.f;
        #pragma unroll
        for (int c0 = 0; c0 < 64; c0 += 8) {
            float v[8];
            #pragma unroll
            for (int q = 0; q < 8; ++q) v[q] = src[(size_t)(c0 + q) * 4096];
            uint pk[4];
            #pragma unroll
            for (int q = 0; q < 4; ++q) {
                ss += v[2*q] * v[2*q] + v[2*q+1] * v[2*q+1];
                uint u0 = __float_as_uint(v[2*q]);   u0 = (u0 + 0x7FFFu + ((u0 >> 16) & 1)) >> 16;
                uint u1 = __float_as_uint(v[2*q+1]); u1 = (u1 + 0x7FFFu + ((u1 >> 16) & 1)) >> 16;
                pk[q] = u0 | (u1 << 16);
            }
            *(uint4*)(dst + c0) = *(const uint4*)pk;     // 16B-aligned (144|16, 2*c0|16)
        }
        const float inv = 1.0f / (sqrtf(ss) + 1e-8f);
        if (r == 9) ainv_s[l] = inv; else binv[r][l] = inv;
    }
    __syncthreads();

    // ---- Phase 2: MFMA band + scaled sum-of-exp
    const int lo = l & 15, hi = l >> 4;
    const int j0 = HP + wib * 16;
    const int arow_l = min(j0 + lo, 63);     // clamp: lanes >63 feed only masked rows
    const bf16x8 a0 = *(const bf16x8*)&at[arow_l][hi * 8];
    const bf16x8 a1 = *(const bf16x8*)&at[arow_l][hi * 8 + 32];

    int jrow[4]; float av[4];
    #pragma unroll
    for (int r = 0; r < 4; ++r) {
        jrow[r] = j0 + hi * 4 + r;
        av[r]   = ainv_s[min(jrow[r], 63)];  // matches clamped A row -> |p| stays <= ~1.03
    }

    float s_acc[4]  = {0.f, 0.f, 0.f, 0.f};
    float sx_acc[4] = {0.f, 0.f, 0.f, 0.f};

    #pragma unroll
    for (int ti = 0; ti < 2; ++ti) {
        const int ntv = wib + ti;            // band of rows [j0, j0+15] spans tiles wib, wib+1
        if (ntv > 3) break;                  // wave 3: single tile (wave-uniform)
        const int col = ntv * 16 + lo;
        float vm[4];
        #pragma unroll
        for (int r = 0; r < 4; ++r) {
            int d = col - jrow[r];
            vm[r] = (jrow[r] < 60 && d >= -HP && d <= HP) ? 1.0f : 0.0f;
        }
        #pragma unroll
        for (int di = 0; di < 9; ++di) {
            const ushort* q = &bt[di][col][hi * 8];
            const bf16x8 bq0 = *(const bf16x8*)q;
            const bf16x8 bq1 = *(const bf16x8*)(q + 32);
            f32x4 acc = __builtin_amdgcn_mfma_f32_16x16x32_bf16(a0, bq0,
                            (f32x4){0.f, 0.f, 0.f, 0.f}, 0, 0, 0);
            acc = __builtin_amdgcn_mfma_f32_16x16x32_bf16(a1, bq1, acc, 0, 0, 0);
            const float bi = binv[di][col];
            #pragma unroll
            for (int r = 0; r < 4; ++r) {
                float p = acc[r] * (av[r] * bi);
                float e = __expf(p);
                s_acc[r]  = fmaf(vm[r], e, s_acc[r]);
                sx_acc[r] = fmaf(vm[r], p, sx_acc[r]);
            }
        }
    }

    // Reduce across the 16 lanes (cols) sharing each output row
    #pragma unroll
    for (int r = 0; r < 4; ++r) {
        #pragma unroll
        for (int off = 1; off < 16; off <<= 1) {
            s_acc[r]  += __shfl_xor(s_acc[r],  off);
            sx_acc[r] += __shfl_xor(sx_acc[r], off);
        }
    }
    if (lo == 0) {
        float csum = 0.f;
        #pragma unroll
        for (int r = 0; r < 4; ++r)
            if (jrow[r] < 60) csum += 81.0f * __logf(s_acc[r]) - sx_acc[r];
        red[wib * 4 + hi] = csum;
    }
    __syncthreads();
    if (t == 0) {
        float t2 = 0.f;
        #pragma unroll
        for (int k = 0; k < 16; ++k) t2 += red[k];
        partials[b] = t2;
    }
}

// ---------------------------------------------------------------------------
// Final reduce: one wave sums 224 partials -> d_out[0] (deterministic)
// ---------------------------------------------------------------------------
__global__ __launch_bounds__(64) void reduce_kernel(const float* __restrict__ partials,
                                                    float* __restrict__ out) {
    const int t = threadIdx.x;
    float s = 0.f;
    #pragma unroll
    for (int k = 0; k < 4; ++k) {
        int idx = k * 64 + t;
        if (idx < 224) s += partials[idx];
    }
    #pragma unroll
    for (int off = 32; off; off >>= 1) s += __shfl_xor(s, off);
    if (t == 0) out[0] = s;
}

extern "C" void kernel_launch(void* const* d_in, const int* in_sizes, int n_in,
                              void* d_out, int out_size, void* d_ws, size_t ws_size,
                              hipStream_t stream) {
    // inputs: 0=featsA(unused) 1=warpedA 2=tensorB 3=warp_grid(unused) 4=patch_size(=9)
    const float* warpedA = (const float*)d_in[1];
    const float* tensorB = (const float*)d_in[2];
    float* partials = (float*)d_ws;          // 224 floats
    float* out = (float*)d_out;

    fused_kernel<<<224, 256, 0, stream>>>(warpedA, tensorB, partials);
    reduce_kernel<<<1, 64, 0, stream>>>(partials, out);
}